// Round 16
// baseline (406.181 us; speedup 1.0000x reference)
//
#include <hip/hip_runtime.h>

#define NB 32
#define NPTS 1024
#define NP 256
#define NS 16
#define NC 256
#define NH 128
#define NOUT 97
#define RP 16   // LDS row stride (floats)
#define NT (NB * NP)   // 8192 tiles

// ---------------------------------------------------------------------------
// Prep. o2 layout for all main matrices: wl[(c*64+m)*2+t] = W[m+64t][c].
// Also zeroes the 3 bucket counters (ws is not re-poisoned between replays).
// ---------------------------------------------------------------------------
__global__ __launch_bounds__(256) void prep_kernel(
    const float* __restrict__ sa_w0, const float* __restrict__ sa_w1,
    const float* __restrict__ sa_w2, const float* __restrict__ fc_w1,
    const float* __restrict__ fc_w2, const float* __restrict__ fc_w3,
    float* __restrict__ w0l, float* __restrict__ w0x,
    float* __restrict__ wl1, float* __restrict__ wl2,
    float* __restrict__ fl1, float* __restrict__ fl2,
    float* __restrict__ fl3, int* __restrict__ cnt)
{
  int t = blockIdx.x * 256 + threadIdx.x;
  if (t < 3) cnt[t] = 0;
  if (t >= 256 * 128) return;
  int c = t >> 7, o = t & 127;
  w0l[(c * 32 + (o & 31)) * 4 + (o >> 5)] = sa_w0[o * 259 + 3 + c];
  if (c < 3) w0x[c * 128 + o] = sa_w0[o * 259 + c];
  if (c < 128) {
    int qi = (c * 64 + (o & 63)) * 2 + (o >> 6);
    wl1[qi] = sa_w1[o * 128 + c];
    wl2[qi] = sa_w2[o * 128 + c];
    fl1[qi] = fc_w1[o * 128 + c];
    fl2[qi] = fc_w2[o * 128 + c];
    fl3[qi] = (o < NOUT) ? fc_w3[o * 128 + c] : 0.0f;
  }
}

// DPP reduction ladder steps (16-lane rows): row_shr:1/2/4/8, bcast15, bcast31
template <int CTRL>
__device__ __forceinline__ float dpp_fmax(float v) {
  float o = __int_as_float(
      __builtin_amdgcn_mov_dpp(__float_as_int(v), CTRL, 0xF, 0xF, true));
  return fmaxf(v, o);   // bound_ctrl: invalid lanes -> 0; v >= 0 so identity
}
template <int CTRL>
__device__ __forceinline__ unsigned dpp_umax(unsigned v) {
  unsigned o = (unsigned)__builtin_amdgcn_mov_dpp((int)v, CTRL, 0xF, 0xF, true);
  return v > o ? v : o;
}

// ---------------------------------------------------------------------------
// Fused FPS + gfeat (Round-14/15 measured version, unchanged).
// ---------------------------------------------------------------------------
__global__ __launch_bounds__(64) void fused_fps_gfeat_kernel(
    const float* __restrict__ xyz, int* __restrict__ inds,
    const float* __restrict__ features, const float* __restrict__ w0l,
    float* __restrict__ G)
{
  __shared__ __align__(16) float smem[NC * RP];   // 16 KB
  const int lane = threadIdx.x;

  if (blockIdx.x < NB) {
    // ------------------------- FPS -------------------------
    const int b = blockIdx.x;
    const float* xb = xyz + b * NPTS * 3;
    float* s_x = smem;
    float* s_y = smem + NPTS;
    float* s_z = smem + 2 * NPTS;
    float px[16], py[16], pz[16], dist[16];
    const float4* src = reinterpret_cast<const float4*>(xb + lane * 48);
#pragma unroll
    for (int q = 0; q < 4; ++q) {
      float4 v0 = src[3 * q], v1 = src[3 * q + 1], v2 = src[3 * q + 2];
      const float xv[4] = {v0.x, v0.w, v1.z, v2.y};
      const float yv[4] = {v0.y, v1.x, v1.w, v2.z};
      const float zv[4] = {v0.z, v1.y, v2.x, v2.w};
#pragma unroll
      for (int t = 0; t < 4; ++t) {
        int j = 4 * q + t;
        px[j] = xv[t]; py[j] = yv[t]; pz[j] = zv[t];
        s_x[lane * 16 + j] = xv[t];
        s_y[lane * 16 + j] = yv[t];
        s_z[lane * 16 + j] = zv[t];
      }
    }
#pragma unroll
    for (int j = 0; j < 16; ++j) dist[j] = 1e10f;
    int far = 0;
    for (int i = 0; i < NP; ++i) {
      if (lane == 0) inds[b * NP + i] = far;
      float cx = s_x[far], cy = s_y[far], cz = s_z[far];   // uniform broadcast
      float bv = -1.0f; int bi = 0;
#pragma unroll
      for (int j = 0; j < 16; ++j) {
#pragma clang fp contract(off)
        float dx = px[j] - cx;
        float dy = py[j] - cy;
        float dz = pz[j] - cz;
        float d = (dx * dx + dy * dy) + dz * dz;
        float nd = fminf(dist[j], d);
        dist[j] = nd;
        if (nd > bv) { bv = nd; bi = lane * 16 + j; }   // ascending j: first max
      }
      float r = bv;
      r = dpp_fmax<0x111>(r);
      r = dpp_fmax<0x112>(r);
      r = dpp_fmax<0x114>(r);
      r = dpp_fmax<0x118>(r);
      r = dpp_fmax<0x142>(r);
      r = dpp_fmax<0x143>(r);
      float gmax = __int_as_float(__builtin_amdgcn_readlane(__float_as_int(r), 63));
      unsigned cand = (bv == gmax) ? ~(unsigned)bi : 0u;
      cand = dpp_umax<0x111>(cand);
      cand = dpp_umax<0x112>(cand);
      cand = dpp_umax<0x114>(cand);
      cand = dpp_umax<0x118>(cand);
      cand = dpp_umax<0x142>(cand);
      cand = dpp_umax<0x143>(cand);
      unsigned cmax = (unsigned)__builtin_amdgcn_readlane((int)cand, 63);
      far = (int)(~cmax);
    }
    return;
  }

  // ------------------------- gfeat (j-split-2) -------------------------
  const int blk = blockIdx.x - NB;
  const int b  = blk >> 6;
  const int n0 = (blk & 63) * 16;
  const int og = lane & 31;
  const int jg = lane >> 5;
  const int joff = jg * 8;
  const float* fb = features + b * NC * NPTS;
#pragma unroll
  for (int r = 0; r < 4; ++r) {
    int c = r * 64 + lane;
    const float4* s4 = reinterpret_cast<const float4*>(fb + c * NPTS + n0);
    float4 v0 = s4[0], v1 = s4[1], v2 = s4[2], v3 = s4[3];
    float* row = smem + c * RP;
    reinterpret_cast<float4*>(row)[0] = v0;
    reinterpret_cast<float4*>(row)[1] = v1;
    reinterpret_cast<float4*>(row)[2] = v2;
    reinterpret_cast<float4*>(row)[3] = v3;
  }
  float acc[4][8];
#pragma unroll
  for (int k = 0; k < 4; ++k)
#pragma unroll
    for (int nn = 0; nn < 8; ++nn) acc[k][nn] = 0.0f;
#pragma unroll 2
  for (int c = 0; c < NC; ++c) {
    const float4 wq = *reinterpret_cast<const float4*>(w0l + (c * 32 + og) * 4);
    const float* row = smem + c * RP + joff;
    const float4 xa = reinterpret_cast<const float4*>(row)[0];
    const float4 xb4 = reinterpret_cast<const float4*>(row)[1];
    const float wk[4] = {wq.x, wq.y, wq.z, wq.w};
    const float xr[8] = {xa.x, xa.y, xa.z, xa.w, xb4.x, xb4.y, xb4.z, xb4.w};
#pragma unroll
    for (int k = 0; k < 4; ++k)
#pragma unroll
      for (int nn = 0; nn < 8; ++nn)
        acc[k][nn] = fmaf(wk[k], xr[nn], acc[k][nn]);
  }
#pragma unroll
  for (int k = 0; k < 4; ++k) {
    int o = og + 32 * k;
    float* gp = G + ((size_t)(b * NPTS + n0 + joff)) * NH + o;
#pragma unroll
    for (int nn = 0; nn < 8; ++nn) gp[nn * NH] = acc[k][nn];
  }
}

// ---------------------------------------------------------------------------
// Ball query + J-class bucketing. One wave per (b,p) tile; bit-identical
// decision math (R2-measured). Writes idxs/gxs/total to global, and buckets
// tile ids by J-class so main can form same-J blocks (phase alignment).
// ---------------------------------------------------------------------------
__global__ __launch_bounds__(256) void ball_kernel(
    const float* __restrict__ xyz, const int* __restrict__ inds,
    int* __restrict__ nbr, float* __restrict__ gx, int* __restrict__ totals,
    int* __restrict__ bucket, int* __restrict__ cnt)
{
  const int wid  = blockIdx.x * 4 + (threadIdx.x >> 6);   // == b*NP + p
  const int lane = threadIdx.x & 63;
  const int b = wid >> 8;
  const float* xb = xyz + b * NPTS * 3;
  const int ci = inds[wid];
  const float cx = xb[ci * 3 + 0], cy = xb[ci * 3 + 1], cz = xb[ci * 3 + 2];
  float nq;
  {
#pragma clang fp contract(off)
    nq = (cx * cx + cy * cy) + cz * cz;
  }
  const float R2 = 0.09f;
  unsigned mask = 0;
  int cntj = 0, firstn = NPTS;
  for (int j = 0; j < 16; ++j) {
#pragma clang fp contract(off)
    int n = lane * 16 + j;   // lane-major: global order == lexicographic
    float x = xb[n * 3 + 0], y = xb[n * 3 + 1], z = xb[n * 3 + 2];
    float nx = (x * x + y * y) + z * z;
    float dt = (cx * x + cy * y) + cz * z;
    float d2 = (nq + nx) - 2.0f * dt;
    if (d2 < R2) { mask |= 1u << j; ++cntj; if (firstn == NPTS) firstn = n; }
  }
  int inc = cntj;
  for (int off = 1; off < 64; off <<= 1) {
    int v = __shfl_up(inc, off);
    if (lane >= off) inc += v;
  }
  int rank  = inc - cntj;
  int total = __shfl(inc, 63);
  for (int j = 0; j < 16; ++j) {
    if (mask & (1u << j)) {
      if (rank < NS) {
        int n = lane * 16 + j;
        nbr[wid * NS + rank] = n;
        float x = xb[n * 3 + 0], y = xb[n * 3 + 1], z = xb[n * 3 + 2];
        gx[wid * 48 + rank * 3 + 0] = (x - cx) / 0.3f;
        gx[wid * 48 + rank * 3 + 1] = (y - cy) / 0.3f;
        gx[wid * 48 + rank * 3 + 2] = (z - cz) / 0.3f;
      }
      ++rank;
    }
  }
  int fmin = firstn;
  for (int off2 = 32; off2 > 0; off2 >>= 1) {
    int ov = __shfl_xor(fmin, off2);
    fmin = min(fmin, ov);
  }
  if (lane < NS && lane >= total) {
    nbr[wid * NS + lane] = fmin;
    float x = xb[fmin * 3 + 0], y = xb[fmin * 3 + 1], z = xb[fmin * 3 + 2];
    gx[wid * 48 + lane * 3 + 0] = (x - cx) / 0.3f;
    gx[wid * 48 + lane * 3 + 1] = (y - cy) / 0.3f;
    gx[wid * 48 + lane * 3 + 2] = (z - cz) / 0.3f;
  }
  if (lane == 0) {
    totals[wid] = total;
    int jc = (total <= 4) ? 0 : ((total <= 8) ? 1 : 2);
    int pos = atomicAdd(&cnt[jc], 1);
    bucket[jc * NT + pos] = wid;
  }
}

// ---------------------------------------------------------------------------
// Templated L0->L1->L2->maxpool for J active neighbor slots (J = 4/8/16),
// with phase barriers (callers guarantee block-uniform J).
// ---------------------------------------------------------------------------
template <int J>
__device__ __forceinline__ void mlp_tiles(
    float* __restrict__ xs, const int lane,
    const float* __restrict__ gbase,
    const int* __restrict__ idxw, const float* __restrict__ gxw,
    const float* __restrict__ w0x, const float* __restrict__ s0v, const float* __restrict__ t0v,
    const float* __restrict__ wl1, const float* __restrict__ s1v, const float* __restrict__ t1v,
    const float* __restrict__ wl2, const float* __restrict__ s2v, const float* __restrict__ t2v,
    float& fo0, float& fo1)
{
  // ---- L0: rows c=lane, c=lane+64, slots 0..J-1 ----
  {
    const float wa0 = w0x[lane],      wb0 = w0x[128 + lane],      wc0 = w0x[256 + lane];
    const float wa1 = w0x[64 + lane], wb1 = w0x[192 + lane],      wc1 = w0x[320 + lane];
    const float ss0 = s0v[lane], tt0 = t0v[lane];
    const float ss1 = s0v[64 + lane], tt1 = t0v[64 + lane];
    float r0[J], r1[J];
#pragma unroll
    for (int j = 0; j < J; ++j) {
      int nj = idxw[j];
      float gxv = gxw[j * 3 + 0], gyv = gxw[j * 3 + 1], gzv = gxw[j * 3 + 2];
      const float* gp = gbase + nj * NH;
      float g0 = gp[lane], g1 = gp[lane + 64];
      float y0 = fmaf(wa0, gxv, fmaf(wb0, gyv, fmaf(wc0, gzv, g0)));
      float y1 = fmaf(wa1, gxv, fmaf(wb1, gyv, fmaf(wc1, gzv, g1)));
      r0[j] = fmaxf(fmaf(y0, ss0, tt0), 0.0f);
      r1[j] = fmaxf(fmaf(y1, ss1, tt1), 0.0f);
    }
#pragma unroll
    for (int q = 0; q < J / 4; ++q) {
      *reinterpret_cast<float4*>(xs + lane * RP + q * 4) =
          make_float4(r0[4 * q], r0[4 * q + 1], r0[4 * q + 2], r0[4 * q + 3]);
      *reinterpret_cast<float4*>(xs + (lane + 64) * RP + q * 4) =
          make_float4(r1[4 * q], r1[4 * q + 1], r1[4 * q + 2], r1[4 * q + 3]);
    }
  }
  __syncthreads();   // phase-align entering the L1 weight stream

  float acc0[J], acc1[J];

  // ---- L1 ----
#pragma unroll
  for (int j = 0; j < J; ++j) { acc0[j] = 0.0f; acc1[j] = 0.0f; }
#pragma unroll 2
  for (int c = 0; c < NH; ++c) {
    const float2 wv = *reinterpret_cast<const float2*>(wl1 + (c * 64 + lane) * 2);
#pragma unroll
    for (int q = 0; q < J / 4; ++q) {
      const float4 xq = *reinterpret_cast<const float4*>(xs + c * RP + q * 4);
      acc0[4 * q + 0] = fmaf(wv.x, xq.x, acc0[4 * q + 0]);
      acc1[4 * q + 0] = fmaf(wv.y, xq.x, acc1[4 * q + 0]);
      acc0[4 * q + 1] = fmaf(wv.x, xq.y, acc0[4 * q + 1]);
      acc1[4 * q + 1] = fmaf(wv.y, xq.y, acc1[4 * q + 1]);
      acc0[4 * q + 2] = fmaf(wv.x, xq.z, acc0[4 * q + 2]);
      acc1[4 * q + 2] = fmaf(wv.y, xq.z, acc1[4 * q + 2]);
      acc0[4 * q + 3] = fmaf(wv.x, xq.w, acc0[4 * q + 3]);
      acc1[4 * q + 3] = fmaf(wv.y, xq.w, acc1[4 * q + 3]);
    }
  }
  // BN+ReLU, write x2 (in-wave LDS ordering: own-plane reads precede writes)
  {
    const float ssa = s1v[lane], tta = t1v[lane];
    const float ssb = s1v[64 + lane], ttb = t1v[64 + lane];
#pragma unroll
    for (int q = 0; q < J / 4; ++q) {
      float4 ra, rb;
      ra.x = fmaxf(fmaf(acc0[4 * q + 0], ssa, tta), 0.0f);
      ra.y = fmaxf(fmaf(acc0[4 * q + 1], ssa, tta), 0.0f);
      ra.z = fmaxf(fmaf(acc0[4 * q + 2], ssa, tta), 0.0f);
      ra.w = fmaxf(fmaf(acc0[4 * q + 3], ssa, tta), 0.0f);
      rb.x = fmaxf(fmaf(acc1[4 * q + 0], ssb, ttb), 0.0f);
      rb.y = fmaxf(fmaf(acc1[4 * q + 1], ssb, ttb), 0.0f);
      rb.z = fmaxf(fmaf(acc1[4 * q + 2], ssb, ttb), 0.0f);
      rb.w = fmaxf(fmaf(acc1[4 * q + 3], ssb, ttb), 0.0f);
      *reinterpret_cast<float4*>(xs + lane * RP + q * 4) = ra;
      *reinterpret_cast<float4*>(xs + (lane + 64) * RP + q * 4) = rb;
    }
  }
  __syncthreads();   // phase-align entering the L2 weight stream

  // ---- L2 ----
#pragma unroll
  for (int j = 0; j < J; ++j) { acc0[j] = 0.0f; acc1[j] = 0.0f; }
#pragma unroll 2
  for (int c = 0; c < NH; ++c) {
    const float2 wv = *reinterpret_cast<const float2*>(wl2 + (c * 64 + lane) * 2);
#pragma unroll
    for (int q = 0; q < J / 4; ++q) {
      const float4 xq = *reinterpret_cast<const float4*>(xs + c * RP + q * 4);
      acc0[4 * q + 0] = fmaf(wv.x, xq.x, acc0[4 * q + 0]);
      acc1[4 * q + 0] = fmaf(wv.y, xq.x, acc1[4 * q + 0]);
      acc0[4 * q + 1] = fmaf(wv.x, xq.y, acc0[4 * q + 1]);
      acc1[4 * q + 1] = fmaf(wv.y, xq.y, acc1[4 * q + 1]);
      acc0[4 * q + 2] = fmaf(wv.x, xq.z, acc0[4 * q + 2]);
      acc1[4 * q + 2] = fmaf(wv.y, xq.z, acc1[4 * q + 2]);
      acc0[4 * q + 3] = fmaf(wv.x, xq.w, acc0[4 * q + 3]);
      acc1[4 * q + 3] = fmaf(wv.y, xq.w, acc1[4 * q + 3]);
    }
  }
  // ---- in-lane maxpool ----
  {
    const float ssa = s2v[lane], tta = t2v[lane];
    const float ssb = s2v[64 + lane], ttb = t2v[64 + lane];
    fo0 = 0.0f; fo1 = 0.0f;
#pragma unroll
    for (int j = 0; j < J; ++j) {
      fo0 = fmaxf(fo0, fmaxf(fmaf(acc0[j], ssa, tta), 0.0f));
      fo1 = fmaxf(fo1, fmaxf(fmaf(acc1[j], ssb, ttb), 0.0f));
    }
  }
}

// FC matvec: h0/h1 += W[lane][c]*f[c], W[lane+64][c]*f[c]; f read uniform.
#define FC_LAYER(WPTR, SRCOFF) \
  h0 = 0.0f; h1 = 0.0f; \
  _Pragma("unroll 4") \
  for (int c4 = 0; c4 < 32; ++c4) { \
    const float4 fq = *reinterpret_cast<const float4*>(xs + (SRCOFF) + c4 * 4); \
    { const float2 wv = *reinterpret_cast<const float2*>((WPTR) + ((c4 * 4 + 0) * 64 + lane) * 2); \
      h0 = fmaf(wv.x, fq.x, h0); h1 = fmaf(wv.y, fq.x, h1); } \
    { const float2 wv = *reinterpret_cast<const float2*>((WPTR) + ((c4 * 4 + 1) * 64 + lane) * 2); \
      h0 = fmaf(wv.x, fq.y, h0); h1 = fmaf(wv.y, fq.y, h1); } \
    { const float2 wv = *reinterpret_cast<const float2*>((WPTR) + ((c4 * 4 + 2) * 64 + lane) * 2); \
      h0 = fmaf(wv.x, fq.z, h0); h1 = fmaf(wv.y, fq.z, h1); } \
    { const float2 wv = *reinterpret_cast<const float2*>((WPTR) + ((c4 * 4 + 3) * 64 + lane) * 2); \
      h0 = fmaf(wv.x, fq.w, h0); h1 = fmaf(wv.y, fq.w, h1); } \
  }

// ---------------------------------------------------------------------------
// Main kernel: 512-thread blocks = 8 waves, tiles assigned via the J-bucket
// permutation so blocks are (almost always) same-J. Block J = max of the 8
// waves' totals (LDS reduce, block-uniform) -> templated path with barriers
// at every weight-stream boundary: same-phase waves share L1 weight lines.
// ---------------------------------------------------------------------------
__global__ __launch_bounds__(512) void main_kernel(
    const int* __restrict__ nbr, const float* __restrict__ gx,
    const int* __restrict__ totals, const int* __restrict__ bucket,
    const int* __restrict__ cnt,
    const float* __restrict__ G,
    const float* __restrict__ w0x, const float* __restrict__ s0v, const float* __restrict__ t0v,
    const float* __restrict__ wl1, const float* __restrict__ s1v, const float* __restrict__ t1v,
    const float* __restrict__ wl2, const float* __restrict__ s2v, const float* __restrict__ t2v,
    const float* __restrict__ fl1, const float* __restrict__ fs1, const float* __restrict__ ft1,
    const float* __restrict__ fl2, const float* __restrict__ fs2, const float* __restrict__ ft2,
    const float* __restrict__ fl3, const float* __restrict__ b3, float* __restrict__ out)
{
  __shared__ __align__(16) float xt[8][NH * RP];   // 64 KB (8 waves)
  __shared__ float gxs[8][NS][3];
  __shared__ int   idxs[8][NS];
  __shared__ int   sh_tot[8];

  const int w    = threadIdx.x >> 6;              // 0..7
  const int lane = threadIdx.x & 63;
  const int g    = blockIdx.x * 8 + w;

  const int c0 = cnt[0], c1 = cnt[1];
  int tile;
  if (g < c0)            tile = bucket[g];
  else if (g < c0 + c1)  tile = bucket[NT + (g - c0)];
  else                   tile = bucket[2 * NT + (g - c0 - c1)];

  const int b = tile >> 8;
  const int p = tile & 255;
  float* xs = &xt[w][0];

  // ---- load precomputed neighbor data; share totals across waves ----
  if (lane < NS) {
    idxs[w][lane] = nbr[tile * NS + lane];
    gxs[w][lane][0] = gx[tile * 48 + lane * 3 + 0];
    gxs[w][lane][1] = gx[tile * 48 + lane * 3 + 1];
    gxs[w][lane][2] = gx[tile * 48 + lane * 3 + 2];
  }
  if (lane == 0) sh_tot[w] = totals[tile];
  __syncthreads();
  int Jb = 0;
#pragma unroll
  for (int r = 0; r < 8; ++r) Jb = max(Jb, sh_tot[r]);   // block-uniform

  // ---- L0 -> L1 -> L2 -> maxpool (barriers inside; uniform branch) ----
  const float* gbase = G + (size_t)b * NPTS * NH;
  float fo0, fo1;
  if (Jb <= 4) {
    mlp_tiles<4>(xs, lane, gbase, idxs[w], &gxs[w][0][0],
                 w0x, s0v, t0v, wl1, s1v, t1v, wl2, s2v, t2v, fo0, fo1);
  } else if (Jb <= 8) {
    mlp_tiles<8>(xs, lane, gbase, idxs[w], &gxs[w][0][0],
                 w0x, s0v, t0v, wl1, s1v, t1v, wl2, s2v, t2v, fo0, fo1);
  } else {
    mlp_tiles<16>(xs, lane, gbase, idxs[w], &gxs[w][0][0],
                  w0x, s0v, t0v, wl1, s1v, t1v, wl2, s2v, t2v, fo0, fo1);
  }
  xs[lane] = fo0;          // f vector -> xs[0..127]
  xs[lane + 64] = fo1;
  __syncthreads();   // phase-align entering the FC1 weight stream

  float h0, h1;

  // ---- FC1: h -> xs[128..255] ----
  FC_LAYER(fl1, 0)
  xs[128 + lane]      = fmaxf(fmaf(h0, fs1[lane],      ft1[lane]),      0.0f);
  xs[128 + lane + 64] = fmaxf(fmaf(h1, fs1[lane + 64], ft1[lane + 64]), 0.0f);
  __syncthreads();   // phase-align entering the FC2 weight stream

  // ---- FC2: f2 -> xs[0..127] ----
  FC_LAYER(fl2, 128)
  xs[lane]      = fmaxf(fmaf(h0, fs2[lane],      ft2[lane]),      0.0f);
  xs[lane + 64] = fmaxf(fmaf(h1, fs2[lane + 64], ft2[lane + 64]), 0.0f);
  __syncthreads();   // phase-align entering the FC3 weight stream

  // ---- FC3 ----
  FC_LAYER(fl3, 0)
  out[(b * NOUT + lane) * NP + p] = h0 + b3[lane];            // lane < 97 always
  if (lane < NOUT - 64)
    out[(b * NOUT + lane + 64) * NP + p] = h1 + b3[lane + 64];
}

extern "C" void kernel_launch(void* const* d_in, const int* in_sizes, int n_in,
                              void* d_out, int out_size, void* d_ws, size_t ws_size,
                              hipStream_t stream) {
  const float* xyz      = (const float*)d_in[0];
  const float* features = (const float*)d_in[1];
  const float* sa_w0 = (const float*)d_in[2];
  const float* sa_s0 = (const float*)d_in[3];
  const float* sa_t0 = (const float*)d_in[4];
  const float* sa_w1 = (const float*)d_in[5];
  const float* sa_s1 = (const float*)d_in[6];
  const float* sa_t1 = (const float*)d_in[7];
  const float* sa_w2 = (const float*)d_in[8];
  const float* sa_s2 = (const float*)d_in[9];
  const float* sa_t2 = (const float*)d_in[10];
  const float* fc_w1 = (const float*)d_in[11];
  const float* fc_s1 = (const float*)d_in[12];
  const float* fc_t1 = (const float*)d_in[13];
  const float* fc_w2 = (const float*)d_in[14];
  const float* fc_s2 = (const float*)d_in[15];
  const float* fc_t2 = (const float*)d_in[16];
  const float* fc_w3 = (const float*)d_in[17];
  const float* fc_b3 = (const float*)d_in[18];
  float* out = (float*)d_out;

  char* ws = (char*)d_ws;
  int* inds = (int*)ws;            ws += (size_t)NT * sizeof(int);
  float* w0l  = (float*)ws;        ws += (size_t)256 * 128 * sizeof(float);
  float* w0x  = (float*)ws;        ws += (size_t)3 * 128 * sizeof(float);
  float* wl1  = (float*)ws;        ws += (size_t)128 * 128 * sizeof(float);
  float* wl2  = (float*)ws;        ws += (size_t)128 * 128 * sizeof(float);
  float* fl1  = (float*)ws;        ws += (size_t)128 * 128 * sizeof(float);
  float* fl2  = (float*)ws;        ws += (size_t)128 * 128 * sizeof(float);
  float* fl3  = (float*)ws;        ws += (size_t)128 * 128 * sizeof(float);
  float* G    = (float*)ws;        ws += (size_t)NB * NPTS * NH * sizeof(float);
  int*   nbr  = (int*)ws;          ws += (size_t)NT * NS * sizeof(int);
  float* gx   = (float*)ws;        ws += (size_t)NT * 48 * sizeof(float);
  int* totals = (int*)ws;          ws += (size_t)NT * sizeof(int);
  int* bucket = (int*)ws;          ws += (size_t)3 * NT * sizeof(int);
  int* cnt    = (int*)ws;          ws += 16 * sizeof(int);

  prep_kernel<<<128, 256, 0, stream>>>(sa_w0, sa_w1, sa_w2, fc_w1, fc_w2, fc_w3,
                                       w0l, w0x, wl1, wl2, fl1, fl2, fl3, cnt);
  fused_fps_gfeat_kernel<<<NB + NB * (NPTS / 16), 64, 0, stream>>>(
      xyz, inds, features, w0l, G);
  ball_kernel<<<NT / 4, 256, 0, stream>>>(xyz, inds, nbr, gx, totals, bucket, cnt);
  main_kernel<<<NT / 8, 512, 0, stream>>>(
      nbr, gx, totals, bucket, cnt, G,
      w0x, sa_s0, sa_t0,
      wl1, sa_s1, sa_t1,
      wl2, sa_s2, sa_t2,
      fl1, fc_s1, fc_t1,
      fl2, fc_s2, fc_t2,
      fl3, fc_b3, out);
}

// Round 17
// 251.909 us; speedup vs baseline: 1.6124x; 1.6124x over previous
//
#include <hip/hip_runtime.h>

#define NB 32
#define NPTS 1024
#define NP 256
#define NS 16
#define NC 256
#define NH 128
#define NOUT 97
#define RP 16   // LDS row stride (floats)
#define NT (NB * NP)   // 8192 tiles

// ---------------------------------------------------------------------------
// Prep. o2 layout for all main matrices: wl[(c*64+m)*2+t] = W[m+64t][c].
// ---------------------------------------------------------------------------
__global__ __launch_bounds__(256) void prep_kernel(
    const float* __restrict__ sa_w0, const float* __restrict__ sa_w1,
    const float* __restrict__ sa_w2, const float* __restrict__ fc_w1,
    const float* __restrict__ fc_w2, const float* __restrict__ fc_w3,
    float* __restrict__ w0l, float* __restrict__ w0x,
    float* __restrict__ wl1, float* __restrict__ wl2,
    float* __restrict__ fl1, float* __restrict__ fl2,
    float* __restrict__ fl3)
{
  int t = blockIdx.x * 256 + threadIdx.x;
  if (t >= 256 * 128) return;
  int c = t >> 7, o = t & 127;
  w0l[(c * 32 + (o & 31)) * 4 + (o >> 5)] = sa_w0[o * 259 + 3 + c];
  if (c < 3) w0x[c * 128 + o] = sa_w0[o * 259 + c];
  if (c < 128) {
    int qi = (c * 64 + (o & 63)) * 2 + (o >> 6);
    wl1[qi] = sa_w1[o * 128 + c];
    wl2[qi] = sa_w2[o * 128 + c];
    fl1[qi] = fc_w1[o * 128 + c];
    fl2[qi] = fc_w2[o * 128 + c];
    fl3[qi] = (o < NOUT) ? fc_w3[o * 128 + c] : 0.0f;
  }
}

// DPP reduction ladder steps (16-lane rows): row_shr:1/2/4/8, bcast15, bcast31
template <int CTRL>
__device__ __forceinline__ float dpp_fmax(float v) {
  float o = __int_as_float(
      __builtin_amdgcn_mov_dpp(__float_as_int(v), CTRL, 0xF, 0xF, true));
  return fmaxf(v, o);   // bound_ctrl: invalid lanes -> 0; v >= 0 so identity
}
template <int CTRL>
__device__ __forceinline__ unsigned dpp_umax(unsigned v) {
  unsigned o = (unsigned)__builtin_amdgcn_mov_dpp((int)v, CTRL, 0xF, 0xF, true);
  return v > o ? v : o;
}

// ---------------------------------------------------------------------------
// Fused FPS + gfeat (measured version, unchanged).
// ---------------------------------------------------------------------------
__global__ __launch_bounds__(64) void fused_fps_gfeat_kernel(
    const float* __restrict__ xyz, int* __restrict__ inds,
    const float* __restrict__ features, const float* __restrict__ w0l,
    float* __restrict__ G)
{
  __shared__ __align__(16) float smem[NC * RP];   // 16 KB
  const int lane = threadIdx.x;

  if (blockIdx.x < NB) {
    // ------------------------- FPS -------------------------
    const int b = blockIdx.x;
    const float* xb = xyz + b * NPTS * 3;
    float* s_x = smem;
    float* s_y = smem + NPTS;
    float* s_z = smem + 2 * NPTS;
    float px[16], py[16], pz[16], dist[16];
    const float4* src = reinterpret_cast<const float4*>(xb + lane * 48);
#pragma unroll
    for (int q = 0; q < 4; ++q) {
      float4 v0 = src[3 * q], v1 = src[3 * q + 1], v2 = src[3 * q + 2];
      const float xv[4] = {v0.x, v0.w, v1.z, v2.y};
      const float yv[4] = {v0.y, v1.x, v1.w, v2.z};
      const float zv[4] = {v0.z, v1.y, v2.x, v2.w};
#pragma unroll
      for (int t = 0; t < 4; ++t) {
        int j = 4 * q + t;
        px[j] = xv[t]; py[j] = yv[t]; pz[j] = zv[t];
        s_x[lane * 16 + j] = xv[t];
        s_y[lane * 16 + j] = yv[t];
        s_z[lane * 16 + j] = zv[t];
      }
    }
#pragma unroll
    for (int j = 0; j < 16; ++j) dist[j] = 1e10f;
    int far = 0;
    for (int i = 0; i < NP; ++i) {
      if (lane == 0) inds[b * NP + i] = far;
      float cx = s_x[far], cy = s_y[far], cz = s_z[far];   // uniform broadcast
      float bv = -1.0f; int bi = 0;
#pragma unroll
      for (int j = 0; j < 16; ++j) {
#pragma clang fp contract(off)
        float dx = px[j] - cx;
        float dy = py[j] - cy;
        float dz = pz[j] - cz;
        float d = (dx * dx + dy * dy) + dz * dz;
        float nd = fminf(dist[j], d);
        dist[j] = nd;
        if (nd > bv) { bv = nd; bi = lane * 16 + j; }   // ascending j: first max
      }
      float r = bv;
      r = dpp_fmax<0x111>(r);
      r = dpp_fmax<0x112>(r);
      r = dpp_fmax<0x114>(r);
      r = dpp_fmax<0x118>(r);
      r = dpp_fmax<0x142>(r);
      r = dpp_fmax<0x143>(r);
      float gmax = __int_as_float(__builtin_amdgcn_readlane(__float_as_int(r), 63));
      unsigned cand = (bv == gmax) ? ~(unsigned)bi : 0u;
      cand = dpp_umax<0x111>(cand);
      cand = dpp_umax<0x112>(cand);
      cand = dpp_umax<0x114>(cand);
      cand = dpp_umax<0x118>(cand);
      cand = dpp_umax<0x142>(cand);
      cand = dpp_umax<0x143>(cand);
      unsigned cmax = (unsigned)__builtin_amdgcn_readlane((int)cand, 63);
      far = (int)(~cmax);
    }
    return;
  }

  // ------------------------- gfeat (j-split-2) -------------------------
  const int blk = blockIdx.x - NB;
  const int b  = blk >> 6;
  const int n0 = (blk & 63) * 16;
  const int og = lane & 31;
  const int jg = lane >> 5;
  const int joff = jg * 8;
  const float* fb = features + b * NC * NPTS;
#pragma unroll
  for (int r = 0; r < 4; ++r) {
    int c = r * 64 + lane;
    const float4* s4 = reinterpret_cast<const float4*>(fb + c * NPTS + n0);
    float4 v0 = s4[0], v1 = s4[1], v2 = s4[2], v3 = s4[3];
    float* row = smem + c * RP;
    reinterpret_cast<float4*>(row)[0] = v0;
    reinterpret_cast<float4*>(row)[1] = v1;
    reinterpret_cast<float4*>(row)[2] = v2;
    reinterpret_cast<float4*>(row)[3] = v3;
  }
  float acc[4][8];
#pragma unroll
  for (int k = 0; k < 4; ++k)
#pragma unroll
    for (int nn = 0; nn < 8; ++nn) acc[k][nn] = 0.0f;
#pragma unroll 2
  for (int c = 0; c < NC; ++c) {
    const float4 wq = *reinterpret_cast<const float4*>(w0l + (c * 32 + og) * 4);
    const float* row = smem + c * RP + joff;
    const float4 xa = reinterpret_cast<const float4*>(row)[0];
    const float4 xb4 = reinterpret_cast<const float4*>(row)[1];
    const float wk[4] = {wq.x, wq.y, wq.z, wq.w};
    const float xr[8] = {xa.x, xa.y, xa.z, xa.w, xb4.x, xb4.y, xb4.z, xb4.w};
#pragma unroll
    for (int k = 0; k < 4; ++k)
#pragma unroll
      for (int nn = 0; nn < 8; ++nn)
        acc[k][nn] = fmaf(wk[k], xr[nn], acc[k][nn]);
  }
#pragma unroll
  for (int k = 0; k < 4; ++k) {
    int o = og + 32 * k;
    float* gp = G + ((size_t)(b * NPTS + n0 + joff)) * NH + o;
#pragma unroll
    for (int nn = 0; nn < 8; ++nn) gp[nn * NH] = acc[k][nn];
  }
}

// ---------------------------------------------------------------------------
// Ball query (bit-identical decision math). NO atomics: writes totals only;
// scan_kernel builds the buckets deterministically.
// ---------------------------------------------------------------------------
__global__ __launch_bounds__(256) void ball_kernel(
    const float* __restrict__ xyz, const int* __restrict__ inds,
    int* __restrict__ nbr, float* __restrict__ gx, int* __restrict__ totals)
{
  const int wid  = blockIdx.x * 4 + (threadIdx.x >> 6);   // == b*NP + p
  const int lane = threadIdx.x & 63;
  const int b = wid >> 8;
  const float* xb = xyz + b * NPTS * 3;
  const int ci = inds[wid];
  const float cx = xb[ci * 3 + 0], cy = xb[ci * 3 + 1], cz = xb[ci * 3 + 2];
  float nq;
  {
#pragma clang fp contract(off)
    nq = (cx * cx + cy * cy) + cz * cz;
  }
  const float R2 = 0.09f;
  unsigned mask = 0;
  int cntj = 0, firstn = NPTS;
  for (int j = 0; j < 16; ++j) {
#pragma clang fp contract(off)
    int n = lane * 16 + j;   // lane-major: global order == lexicographic
    float x = xb[n * 3 + 0], y = xb[n * 3 + 1], z = xb[n * 3 + 2];
    float nx = (x * x + y * y) + z * z;
    float dt = (cx * x + cy * y) + cz * z;
    float d2 = (nq + nx) - 2.0f * dt;
    if (d2 < R2) { mask |= 1u << j; ++cntj; if (firstn == NPTS) firstn = n; }
  }
  int inc = cntj;
  for (int off = 1; off < 64; off <<= 1) {
    int v = __shfl_up(inc, off);
    if (lane >= off) inc += v;
  }
  int rank  = inc - cntj;
  int total = __shfl(inc, 63);
  for (int j = 0; j < 16; ++j) {
    if (mask & (1u << j)) {
      if (rank < NS) {
        int n = lane * 16 + j;
        nbr[wid * NS + rank] = n;
        float x = xb[n * 3 + 0], y = xb[n * 3 + 1], z = xb[n * 3 + 2];
        gx[wid * 48 + rank * 3 + 0] = (x - cx) / 0.3f;
        gx[wid * 48 + rank * 3 + 1] = (y - cy) / 0.3f;
        gx[wid * 48 + rank * 3 + 2] = (z - cz) / 0.3f;
      }
      ++rank;
    }
  }
  int fmin = firstn;
  for (int off2 = 32; off2 > 0; off2 >>= 1) {
    int ov = __shfl_xor(fmin, off2);
    fmin = min(fmin, ov);
  }
  if (lane < NS && lane >= total) {
    nbr[wid * NS + lane] = fmin;
    float x = xb[fmin * 3 + 0], y = xb[fmin * 3 + 1], z = xb[fmin * 3 + 2];
    gx[wid * 48 + lane * 3 + 0] = (x - cx) / 0.3f;
    gx[wid * 48 + lane * 3 + 1] = (y - cy) / 0.3f;
    gx[wid * 48 + lane * 3 + 2] = (z - cz) / 0.3f;
  }
  if (lane == 0) totals[wid] = total;
}

// ---------------------------------------------------------------------------
// Deterministic bucket build: one block, 1024 threads, 8 tiles each.
// Packed-u64 scan (3 class counts x 21 bits). Stable within class.
// ---------------------------------------------------------------------------
__global__ __launch_bounds__(1024) void scan_kernel(
    const int* __restrict__ totals, int* __restrict__ bucket, int* __restrict__ cnt)
{
  __shared__ unsigned long long ssum[16];
  const int t = threadIdx.x;
  int cls[8];
  unsigned long long local = 0;
#pragma unroll
  for (int k = 0; k < 8; ++k) {
    int tot = totals[t * 8 + k];
    int jc = (tot <= 4) ? 0 : ((tot <= 8) ? 1 : 2);
    cls[k] = jc;
    local += 1ull << (jc * 21);
  }
  unsigned long long inc = local;
  for (int off = 1; off < 64; off <<= 1) {
    unsigned long long v = __shfl_up(inc, off);
    if ((t & 63) >= off) inc += v;
  }
  if ((t & 63) == 63) ssum[t >> 6] = inc;
  __syncthreads();
  if (t == 0) {
    unsigned long long run = 0;
    for (int i = 0; i < 16; ++i) { unsigned long long v = ssum[i]; ssum[i] = run; run += v; }
    cnt[0] = (int)(run & 0x1FFFFFull);
    cnt[1] = (int)((run >> 21) & 0x1FFFFFull);
    cnt[2] = (int)((run >> 42) & 0x1FFFFFull);
  }
  __syncthreads();
  unsigned long long excl = (inc - local) + ssum[t >> 6];
  int p0 = (int)(excl & 0x1FFFFFull);
  int p1 = (int)((excl >> 21) & 0x1FFFFFull);
  int p2 = (int)((excl >> 42) & 0x1FFFFFull);
#pragma unroll
  for (int k = 0; k < 8; ++k) {
    int id = t * 8 + k;
    if (cls[k] == 0)      { bucket[p0] = id; ++p0; }
    else if (cls[k] == 1) { bucket[NT + p1] = id; ++p1; }
    else                  { bucket[2 * NT + p2] = id; ++p2; }
  }
}

// ---------------------------------------------------------------------------
// 16-slot MLP core (L0 -> L1 -> L2), o2 scheme: lane owns o in {lane,lane+64},
// all 16 slots in registers. acc left raw (pre-BN) for per-tile maxpool.
// ---------------------------------------------------------------------------
__device__ __forceinline__ void mlp16(
    float* __restrict__ xs, const int lane,
    const float* __restrict__ G, const int* __restrict__ idxw,
    const float* __restrict__ gxw,
    const float* __restrict__ w0x, const float* __restrict__ s0v, const float* __restrict__ t0v,
    const float* __restrict__ wl1, const float* __restrict__ s1v, const float* __restrict__ t1v,
    const float* __restrict__ wl2,
    float acc0[16], float acc1[16])
{
  // ---- L0 ----
  {
    const float wa0 = w0x[lane],      wb0 = w0x[128 + lane],      wc0 = w0x[256 + lane];
    const float wa1 = w0x[64 + lane], wb1 = w0x[192 + lane],      wc1 = w0x[320 + lane];
    const float ss0 = s0v[lane], tt0 = t0v[lane];
    const float ss1 = s0v[64 + lane], tt1 = t0v[64 + lane];
    float r0[16], r1[16];
#pragma unroll
    for (int j = 0; j < 16; ++j) {
      int gj = idxw[j];                       // prefolded b*NPTS + nbr
      float gxv = gxw[j * 3 + 0], gyv = gxw[j * 3 + 1], gzv = gxw[j * 3 + 2];
      const float* gp = G + (size_t)gj * NH;
      float g0 = gp[lane], g1 = gp[lane + 64];
      float y0 = fmaf(wa0, gxv, fmaf(wb0, gyv, fmaf(wc0, gzv, g0)));
      float y1 = fmaf(wa1, gxv, fmaf(wb1, gyv, fmaf(wc1, gzv, g1)));
      r0[j] = fmaxf(fmaf(y0, ss0, tt0), 0.0f);
      r1[j] = fmaxf(fmaf(y1, ss1, tt1), 0.0f);
    }
#pragma unroll
    for (int q = 0; q < 4; ++q) {
      *reinterpret_cast<float4*>(xs + lane * RP + q * 4) =
          make_float4(r0[4 * q], r0[4 * q + 1], r0[4 * q + 2], r0[4 * q + 3]);
      *reinterpret_cast<float4*>(xs + (lane + 64) * RP + q * 4) =
          make_float4(r1[4 * q], r1[4 * q + 1], r1[4 * q + 2], r1[4 * q + 3]);
    }
  }

  // ---- L1 ----
#pragma unroll
  for (int j = 0; j < 16; ++j) { acc0[j] = 0.0f; acc1[j] = 0.0f; }
#pragma unroll 2
  for (int c = 0; c < NH; ++c) {
    const float2 wv = *reinterpret_cast<const float2*>(wl1 + (c * 64 + lane) * 2);
#pragma unroll
    for (int q = 0; q < 4; ++q) {
      const float4 xq = *reinterpret_cast<const float4*>(xs + c * RP + q * 4);
      acc0[4 * q + 0] = fmaf(wv.x, xq.x, acc0[4 * q + 0]);
      acc1[4 * q + 0] = fmaf(wv.y, xq.x, acc1[4 * q + 0]);
      acc0[4 * q + 1] = fmaf(wv.x, xq.y, acc0[4 * q + 1]);
      acc1[4 * q + 1] = fmaf(wv.y, xq.y, acc1[4 * q + 1]);
      acc0[4 * q + 2] = fmaf(wv.x, xq.z, acc0[4 * q + 2]);
      acc1[4 * q + 2] = fmaf(wv.y, xq.z, acc1[4 * q + 2]);
      acc0[4 * q + 3] = fmaf(wv.x, xq.w, acc0[4 * q + 3]);
      acc1[4 * q + 3] = fmaf(wv.y, xq.w, acc1[4 * q + 3]);
    }
  }
  // BN+ReLU, write x2 (in-wave LDS ordering: own-plane reads precede writes)
  {
    const float ssa = s1v[lane], tta = t1v[lane];
    const float ssb = s1v[64 + lane], ttb = t1v[64 + lane];
#pragma unroll
    for (int q = 0; q < 4; ++q) {
      float4 ra, rb;
      ra.x = fmaxf(fmaf(acc0[4 * q + 0], ssa, tta), 0.0f);
      ra.y = fmaxf(fmaf(acc0[4 * q + 1], ssa, tta), 0.0f);
      ra.z = fmaxf(fmaf(acc0[4 * q + 2], ssa, tta), 0.0f);
      ra.w = fmaxf(fmaf(acc0[4 * q + 3], ssa, tta), 0.0f);
      rb.x = fmaxf(fmaf(acc1[4 * q + 0], ssb, ttb), 0.0f);
      rb.y = fmaxf(fmaf(acc1[4 * q + 1], ssb, ttb), 0.0f);
      rb.z = fmaxf(fmaf(acc1[4 * q + 2], ssb, ttb), 0.0f);
      rb.w = fmaxf(fmaf(acc1[4 * q + 3], ssb, ttb), 0.0f);
      *reinterpret_cast<float4*>(xs + lane * RP + q * 4) = ra;
      *reinterpret_cast<float4*>(xs + (lane + 64) * RP + q * 4) = rb;
    }
  }

  // ---- L2 (raw acc; BN+maxpool done by caller per tile) ----
#pragma unroll
  for (int j = 0; j < 16; ++j) { acc0[j] = 0.0f; acc1[j] = 0.0f; }
#pragma unroll 2
  for (int c = 0; c < NH; ++c) {
    const float2 wv = *reinterpret_cast<const float2*>(wl2 + (c * 64 + lane) * 2);
#pragma unroll
    for (int q = 0; q < 4; ++q) {
      const float4 xq = *reinterpret_cast<const float4*>(xs + c * RP + q * 4);
      acc0[4 * q + 0] = fmaf(wv.x, xq.x, acc0[4 * q + 0]);
      acc1[4 * q + 0] = fmaf(wv.y, xq.x, acc1[4 * q + 0]);
      acc0[4 * q + 1] = fmaf(wv.x, xq.y, acc0[4 * q + 1]);
      acc1[4 * q + 1] = fmaf(wv.y, xq.y, acc1[4 * q + 1]);
      acc0[4 * q + 2] = fmaf(wv.x, xq.z, acc0[4 * q + 2]);
      acc1[4 * q + 2] = fmaf(wv.y, xq.z, acc1[4 * q + 2]);
      acc0[4 * q + 3] = fmaf(wv.x, xq.w, acc0[4 * q + 3]);
      acc1[4 * q + 3] = fmaf(wv.y, xq.w, acc1[4 * q + 3]);
    }
  }
}

// ---------------------------------------------------------------------------
// Epilogue for TPW tiles (16/TPW slots each): maxpool per tile -> FC1/2/3.
// f vectors at xs[k*128..], h vectors at xs[TPW*128 + k*128..].
// ---------------------------------------------------------------------------
template <int TPW>
__device__ __forceinline__ void fc_epilogue(
    float* __restrict__ xs, const int lane, const int tiles[4],
    float acc0[16], float acc1[16],
    const float* __restrict__ s2v, const float* __restrict__ t2v,
    const float* __restrict__ fl1, const float* __restrict__ fs1, const float* __restrict__ ft1,
    const float* __restrict__ fl2, const float* __restrict__ fs2, const float* __restrict__ ft2,
    const float* __restrict__ fl3, const float* __restrict__ b3, float* __restrict__ out)
{
  constexpr int SPT = 16 / TPW;
  // ---- per-tile BN+ReLU+maxpool -> f vectors ----
  {
    const float ssa = s2v[lane], tta = t2v[lane];
    const float ssb = s2v[64 + lane], ttb = t2v[64 + lane];
#pragma unroll
    for (int k = 0; k < TPW; ++k) {
      float fo0 = 0.0f, fo1 = 0.0f;
#pragma unroll
      for (int r = 0; r < SPT; ++r) {
        fo0 = fmaxf(fo0, fmaxf(fmaf(acc0[k * SPT + r], ssa, tta), 0.0f));
        fo1 = fmaxf(fo1, fmaxf(fmaf(acc1[k * SPT + r], ssb, ttb), 0.0f));
      }
      xs[k * 128 + lane] = fo0;
      xs[k * 128 + 64 + lane] = fo1;
    }
  }
  constexpr int HB = TPW * 128;

  float h0[TPW], h1[TPW];

  // ---- FC1 ----
#pragma unroll
  for (int k = 0; k < TPW; ++k) { h0[k] = 0.0f; h1[k] = 0.0f; }
#pragma unroll 4
  for (int c4 = 0; c4 < 32; ++c4) {
    float4 fq[TPW];
#pragma unroll
    for (int k = 0; k < TPW; ++k)
      fq[k] = *reinterpret_cast<const float4*>(xs + k * 128 + c4 * 4);
#pragma unroll
    for (int cc = 0; cc < 4; ++cc) {
      const float2 wv = *reinterpret_cast<const float2*>(fl1 + ((c4 * 4 + cc) * 64 + lane) * 2);
#pragma unroll
      for (int k = 0; k < TPW; ++k) {
        float fv = (cc == 0) ? fq[k].x : (cc == 1) ? fq[k].y : (cc == 2) ? fq[k].z : fq[k].w;
        h0[k] = fmaf(wv.x, fv, h0[k]);
        h1[k] = fmaf(wv.y, fv, h1[k]);
      }
    }
  }
#pragma unroll
  for (int k = 0; k < TPW; ++k) {
    xs[HB + k * 128 + lane]      = fmaxf(fmaf(h0[k], fs1[lane],      ft1[lane]),      0.0f);
    xs[HB + k * 128 + 64 + lane] = fmaxf(fmaf(h1[k], fs1[lane + 64], ft1[lane + 64]), 0.0f);
  }

  // ---- FC2 ----
#pragma unroll
  for (int k = 0; k < TPW; ++k) { h0[k] = 0.0f; h1[k] = 0.0f; }
#pragma unroll 4
  for (int c4 = 0; c4 < 32; ++c4) {
    float4 fq[TPW];
#pragma unroll
    for (int k = 0; k < TPW; ++k)
      fq[k] = *reinterpret_cast<const float4*>(xs + HB + k * 128 + c4 * 4);
#pragma unroll
    for (int cc = 0; cc < 4; ++cc) {
      const float2 wv = *reinterpret_cast<const float2*>(fl2 + ((c4 * 4 + cc) * 64 + lane) * 2);
#pragma unroll
      for (int k = 0; k < TPW; ++k) {
        float fv = (cc == 0) ? fq[k].x : (cc == 1) ? fq[k].y : (cc == 2) ? fq[k].z : fq[k].w;
        h0[k] = fmaf(wv.x, fv, h0[k]);
        h1[k] = fmaf(wv.y, fv, h1[k]);
      }
    }
  }
#pragma unroll
  for (int k = 0; k < TPW; ++k) {
    xs[k * 128 + lane]      = fmaxf(fmaf(h0[k], fs2[lane],      ft2[lane]),      0.0f);
    xs[k * 128 + 64 + lane] = fmaxf(fmaf(h1[k], fs2[lane + 64], ft2[lane + 64]), 0.0f);
  }

  // ---- FC3 ----
#pragma unroll
  for (int k = 0; k < TPW; ++k) { h0[k] = 0.0f; h1[k] = 0.0f; }
#pragma unroll 4
  for (int c4 = 0; c4 < 32; ++c4) {
    float4 fq[TPW];
#pragma unroll
    for (int k = 0; k < TPW; ++k)
      fq[k] = *reinterpret_cast<const float4*>(xs + k * 128 + c4 * 4);
#pragma unroll
    for (int cc = 0; cc < 4; ++cc) {
      const float2 wv = *reinterpret_cast<const float2*>(fl3 + ((c4 * 4 + cc) * 64 + lane) * 2);
#pragma unroll
      for (int k = 0; k < TPW; ++k) {
        float fv = (cc == 0) ? fq[k].x : (cc == 1) ? fq[k].y : (cc == 2) ? fq[k].z : fq[k].w;
        h0[k] = fmaf(wv.x, fv, h0[k]);
        h1[k] = fmaf(wv.y, fv, h1[k]);
      }
    }
  }
#pragma unroll
  for (int k = 0; k < TPW; ++k) {
    int tk = tiles[k];                      // compile-time k: stays in regs
    int b = tk >> 8, p = tk & 255;
    out[(b * NOUT + lane) * NP + p] = h0[k] + b3[lane];   // lane < 97 always
    if (lane < NOUT - 64)
      out[(b * NOUT + lane + 64) * NP + p] = h1[k] + b3[lane + 64];
  }
}

// ---------------------------------------------------------------------------
// Main kernel: 512-thread blocks = 8 independent waves (no barriers). Each
// wave carries a 16-slot task: 4 x J4-tiles, 2 x J8-tiles, or 1 x J16-tile,
// assigned via the class buckets. Uniform MLP core; weight traffic per tile
// divided by the pack factor. Partial packs pad with clones (duplicate
// output writes of identical values).
// ---------------------------------------------------------------------------
__global__ __launch_bounds__(512) void main_kernel(
    const int* __restrict__ nbr, const float* __restrict__ gx,
    const int* __restrict__ bucket, const int* __restrict__ cnt,
    const float* __restrict__ G,
    const float* __restrict__ w0x, const float* __restrict__ s0v, const float* __restrict__ t0v,
    const float* __restrict__ wl1, const float* __restrict__ s1v, const float* __restrict__ t1v,
    const float* __restrict__ wl2, const float* __restrict__ s2v, const float* __restrict__ t2v,
    const float* __restrict__ fl1, const float* __restrict__ fs1, const float* __restrict__ ft1,
    const float* __restrict__ fl2, const float* __restrict__ fs2, const float* __restrict__ ft2,
    const float* __restrict__ fl3, const float* __restrict__ b3, float* __restrict__ out)
{
  __shared__ __align__(16) float xt[8][NH * RP];   // 64 KB (8 waves)
  __shared__ float gxs[8][NS][3];
  __shared__ int   idxs[8][NS];

  const int w    = threadIdx.x >> 6;              // 0..7
  const int lane = threadIdx.x & 63;
  const int g    = blockIdx.x * 8 + w;

  const int c0 = cnt[0], c1 = cnt[1], c2 = cnt[2];
  const int npack4 = (c0 + 3) >> 2;
  const int npack8 = (c1 + 1) >> 1;
  if (g >= npack4 + npack8 + c2) return;          // no barriers: early exit ok

  int tiles[4];
  int tpw;
  if (g < npack4) {
    tpw = 4;
    tiles[0] = bucket[min(4 * g + 0, c0 - 1)];
    tiles[1] = bucket[min(4 * g + 1, c0 - 1)];
    tiles[2] = bucket[min(4 * g + 2, c0 - 1)];
    tiles[3] = bucket[min(4 * g + 3, c0 - 1)];
  } else if (g < npack4 + npack8) {
    tpw = 2;
    int base = g - npack4;
    tiles[0] = bucket[NT + min(2 * base + 0, c1 - 1)];
    tiles[1] = bucket[NT + min(2 * base + 1, c1 - 1)];
    tiles[2] = tiles[0]; tiles[3] = tiles[1];
  } else {
    tpw = 1;
    tiles[0] = bucket[2 * NT + (g - npack4 - npack8)];
    tiles[1] = tiles[2] = tiles[3] = tiles[0];
  }

  float* xs = &xt[w][0];

  // ---- prologue: gather 16 (tile, slot) pairs into LDS ----
  if (lane < 16) {
    int tk, r;
    if (tpw == 4)      { tk = (lane < 4) ? tiles[0] : (lane < 8) ? tiles[1]
                              : (lane < 12) ? tiles[2] : tiles[3];  r = lane & 3; }
    else if (tpw == 2) { tk = (lane < 8) ? tiles[0] : tiles[1];     r = lane & 7; }
    else               { tk = tiles[0];                              r = lane; }
    int bk = tk >> 8;
    idxs[w][lane] = bk * NPTS + nbr[tk * NS + r];
    gxs[w][lane][0] = gx[tk * 48 + r * 3 + 0];
    gxs[w][lane][1] = gx[tk * 48 + r * 3 + 1];
    gxs[w][lane][2] = gx[tk * 48 + r * 3 + 2];
  }
  // single wave owns its LDS plane: in-wave lgkmcnt orders write->read

  float acc0[16], acc1[16];
  mlp16(xs, lane, G, idxs[w], &gxs[w][0][0],
        w0x, s0v, t0v, wl1, s1v, t1v, wl2, acc0, acc1);

  if (tpw == 4) {
    fc_epilogue<4>(xs, lane, tiles, acc0, acc1, s2v, t2v,
                   fl1, fs1, ft1, fl2, fs2, ft2, fl3, b3, out);
  } else if (tpw == 2) {
    fc_epilogue<2>(xs, lane, tiles, acc0, acc1, s2v, t2v,
                   fl1, fs1, ft1, fl2, fs2, ft2, fl3, b3, out);
  } else {
    fc_epilogue<1>(xs, lane, tiles, acc0, acc1, s2v, t2v,
                   fl1, fs1, ft1, fl2, fs2, ft2, fl3, b3, out);
  }
}

extern "C" void kernel_launch(void* const* d_in, const int* in_sizes, int n_in,
                              void* d_out, int out_size, void* d_ws, size_t ws_size,
                              hipStream_t stream) {
  const float* xyz      = (const float*)d_in[0];
  const float* features = (const float*)d_in[1];
  const float* sa_w0 = (const float*)d_in[2];
  const float* sa_s0 = (const float*)d_in[3];
  const float* sa_t0 = (const float*)d_in[4];
  const float* sa_w1 = (const float*)d_in[5];
  const float* sa_s1 = (const float*)d_in[6];
  const float* sa_t1 = (const float*)d_in[7];
  const float* sa_w2 = (const float*)d_in[8];
  const float* sa_s2 = (const float*)d_in[9];
  const float* sa_t2 = (const float*)d_in[10];
  const float* fc_w1 = (const float*)d_in[11];
  const float* fc_s1 = (const float*)d_in[12];
  const float* fc_t1 = (const float*)d_in[13];
  const float* fc_w2 = (const float*)d_in[14];
  const float* fc_s2 = (const float*)d_in[15];
  const float* fc_t2 = (const float*)d_in[16];
  const float* fc_w3 = (const float*)d_in[17];
  const float* fc_b3 = (const float*)d_in[18];
  float* out = (float*)d_out;

  char* ws = (char*)d_ws;
  int* inds = (int*)ws;            ws += (size_t)NT * sizeof(int);
  float* w0l  = (float*)ws;        ws += (size_t)256 * 128 * sizeof(float);
  float* w0x  = (float*)ws;        ws += (size_t)3 * 128 * sizeof(float);
  float* wl1  = (float*)ws;        ws += (size_t)128 * 128 * sizeof(float);
  float* wl2  = (float*)ws;        ws += (size_t)128 * 128 * sizeof(float);
  float* fl1  = (float*)ws;        ws += (size_t)128 * 128 * sizeof(float);
  float* fl2  = (float*)ws;        ws += (size_t)128 * 128 * sizeof(float);
  float* fl3  = (float*)ws;        ws += (size_t)128 * 128 * sizeof(float);
  float* G    = (float*)ws;        ws += (size_t)NB * NPTS * NH * sizeof(float);
  int*   nbr  = (int*)ws;          ws += (size_t)NT * NS * sizeof(int);
  float* gx   = (float*)ws;        ws += (size_t)NT * 48 * sizeof(float);
  int* totals = (int*)ws;          ws += (size_t)NT * sizeof(int);
  int* bucket = (int*)ws;          ws += (size_t)3 * NT * sizeof(int);
  int* cnt    = (int*)ws;          ws += 16 * sizeof(int);

  prep_kernel<<<128, 256, 0, stream>>>(sa_w0, sa_w1, sa_w2, fc_w1, fc_w2, fc_w3,
                                       w0l, w0x, wl1, wl2, fl1, fl2, fl3);
  fused_fps_gfeat_kernel<<<NB + NB * (NPTS / 16), 64, 0, stream>>>(
      xyz, inds, features, w0l, G);
  ball_kernel<<<NT / 4, 256, 0, stream>>>(xyz, inds, nbr, gx, totals);
  scan_kernel<<<1, 1024, 0, stream>>>(totals, bucket, cnt);
  main_kernel<<<NT / 8, 512, 0, stream>>>(
      nbr, gx, bucket, cnt, G,
      w0x, sa_s0, sa_t0,
      wl1, sa_s1, sa_t1,
      wl2, sa_s2, sa_t2,
      fl1, fc_s1, fc_t1,
      fl2, fc_s2, fc_t2,
      fl3, fc_b3, out);
}